// Round 13
// baseline (815.679 us; speedup 1.0000x reference)
//
#include <hip/hip_runtime.h>
#include <math.h>

#define B_ 32
#define S_ 256
#define E_ 768
#define H_ 12
#define L_ 2
#define FF_ 2048
#define NEGV -1e30f

typedef __attribute__((ext_vector_type(8))) short bf16x8;
typedef __attribute__((ext_vector_type(4))) float f32x4;

// ---------- bf16 split helpers ----------
__device__ __forceinline__ short bf16_rne(float x) {
  unsigned u = __float_as_uint(x);
  u += 0x7fffu + ((u >> 16) & 1u);
  return (short)(u >> 16);
}
__device__ __forceinline__ float bf16_to_f32(short h) {
  return __uint_as_float(((unsigned)(unsigned short)h) << 16);
}
__device__ __forceinline__ void split_bf16(float v, short& h, short& l) {
  h = bf16_rne(v);
  l = bf16_rne(v - bf16_to_f32(h));
}

__device__ __forceinline__ void gl2lds16(const short* g, short* s) {
  __builtin_amdgcn_global_load_lds((const __attribute__((address_space(1))) void*)g,
                                   (__attribute__((address_space(3))) void*)s, 16, 0, 0);
}

// ---------------- block-wide sum over 256 threads ----------------
__device__ __forceinline__ float block_sum256(float v) {
  __shared__ float sh[4];
  int lane = threadIdx.x & 63, w = threadIdx.x >> 6;
#pragma unroll
  for (int off = 32; off; off >>= 1) v += __shfl_down(v, off);
  if (lane == 0) sh[w] = v;
  __syncthreads();
  float tot = sh[0] + sh[1] + sh[2] + sh[3];
  __syncthreads();
  return tot;
}

// ---------------- embed + LN (emits f32 + bf16 split planes) ----------------
__global__ __launch_bounds__(256) void embed_ln_kernel(
    const float* __restrict__ tok, const int* __restrict__ pos,
    const int* __restrict__ typ, const float* __restrict__ pe,
    const float* __restrict__ temb, const float* __restrict__ w,
    const float* __restrict__ b, float* __restrict__ out,
    short* __restrict__ ohi, short* __restrict__ olo) {
  int row = blockIdx.x;
  int t = threadIdx.x;
  int p = pos[row], ty = typ[row];
  const float* tr = tok + (size_t)row * E_;
  const float* pr = pe + (size_t)p * E_;
  const float* yr = temb + (size_t)ty * E_;
  float v0 = tr[t] + pr[t] + yr[t];
  float v1 = tr[t + 256] + pr[t + 256] + yr[t + 256];
  float v2 = tr[t + 512] + pr[t + 512] + yr[t + 512];
  float m = block_sum256(v0 + v1 + v2) * (1.f / E_);
  float d0 = v0 - m, d1 = v1 - m, d2 = v2 - m;
  float var = block_sum256(d0 * d0 + d1 * d1 + d2 * d2) * (1.f / E_);
  float rs = 1.f / sqrtf(var + 1e-5f);
  size_t base = (size_t)row * E_;
  float r0 = d0 * rs * w[t] + b[t];
  float r1 = d1 * rs * w[t + 256] + b[t + 256];
  float r2 = d2 * rs * w[t + 512] + b[t + 512];
  out[base + t] = r0; out[base + t + 256] = r1; out[base + t + 512] = r2;
  short h, l;
  split_bf16(r0, h, l); ohi[base + t] = h; olo[base + t] = l;
  split_bf16(r1, h, l); ohi[base + t + 256] = h; olo[base + t + 256] = l;
  split_bf16(r2, h, l); ohi[base + t + 512] = h; olo[base + t + 512] = l;
}

// ---------------- LN (emits optional f32 + bf16 split planes) ---------------
__global__ __launch_bounds__(256) void ln_kernel(
    const float* __restrict__ in, const float* __restrict__ w,
    const float* __restrict__ b, float* __restrict__ out,
    short* __restrict__ ohi, short* __restrict__ olo) {
  int row = blockIdx.x;
  int t = threadIdx.x;
  const float* p = in + (size_t)row * E_;
  float v0 = p[t], v1 = p[t + 256], v2 = p[t + 512];
  float m = block_sum256(v0 + v1 + v2) * (1.f / E_);
  float d0 = v0 - m, d1 = v1 - m, d2 = v2 - m;
  float var = block_sum256(d0 * d0 + d1 * d1 + d2 * d2) * (1.f / E_);
  float rs = 1.f / sqrtf(var + 1e-5f);
  size_t base = (size_t)row * E_;
  float r0 = d0 * rs * w[t] + b[t];
  float r1 = d1 * rs * w[t + 256] + b[t + 256];
  float r2 = d2 * rs * w[t + 512] + b[t + 512];
  if (out) {
    out[base + t] = r0; out[base + t + 256] = r1; out[base + t + 512] = r2;
  }
  short h, l;
  split_bf16(r0, h, l); ohi[base + t] = h; olo[base + t] = l;
  split_bf16(r1, h, l); ohi[base + t + 256] = h; olo[base + t + 256] = l;
  split_bf16(r2, h, l); ohi[base + t + 512] = h; olo[base + t + 512] = l;
}

// ---------------- weight split: f32 -> (hi, lo) bf16 planes ----------------
__global__ __launch_bounds__(256) void split_kernel(
    const float* __restrict__ src, short* __restrict__ hi,
    short* __restrict__ lo, int n4) {
  int i = blockIdx.x * 256 + threadIdx.x;
  if (i >= n4) return;
  float4 v = ((const float4*)src)[i];
  short4 h, l;
  split_bf16(v.x, h.x, l.x);
  split_bf16(v.y, h.y, l.y);
  split_bf16(v.z, h.z, l.z);
  split_bf16(v.w, h.w, l.w);
  ((short4*)hi)[i] = h;
  ((short4*)lo)[i] = l;
}

// ---------------- 256-row 8-wave split-bf16 MFMA GEMM -----------------------
// Block 256 x BN_, 512 thr = 8 waves, joint 3-pass.  Chunk-mapped staging
// (chunk = 32 shorts of one plane row), counted-vmcnt dbuf schedule, raw
// s_barrier.  Grid must be exactly (M/256)*(N/BN_) = 256 blocks (1/CU).
// BN in {288 (qkv), 256 (lin1), 96 (out/lin2/dense)}.
template <int BN_, int WM_, int WN_, int ACT, int RES, int OSPLIT>
__global__ __launch_bounds__(512, 2) void gemm_big(
    const short* __restrict__ Ahi, const short* __restrict__ Alo,
    const short* __restrict__ Whi, const short* __restrict__ Wlo,
    const float* __restrict__ bias, const float* __restrict__ Rres,
    float* __restrict__ Cf, short* __restrict__ Chi, short* __restrict__ Clo,
    int M, int N, int K, int nx, int cpx) {
  constexpr int BM_ = 256;
  constexpr int MR = WM_ / 16, NR = WN_ / 16;
  constexpr int NWC = BN_ / WN_;
  constexpr int CHUNKS = 2 * BM_ + 2 * BN_;     // 1088 / 1024 / 704
  constexpr int OPS_FULL = CHUNKS / 128;        // 8 / 8 / 5
  constexpr int REM = CHUNKS - OPS_FULL * 128;  // 64 / 0 / 64
  constexpr int BUFSH = CHUNKS * 32;

  __shared__ short lds[2 * BUFSH];
  const int t = threadIdx.x;
  const int l = t & 63;
  const int w = t >> 6;
  const int wr = w / NWC, wc = w % NWC;
  const int li = l & 15, lh = l >> 4;

  int id = blockIdx.x;
  int id2 = (id & 7) * cpx + (id >> 3);
  const int n0 = (id2 % nx) * BN_, m0 = (id2 / nx) * BM_;

  // ---- staging source pointers (chunk map, XOR-swizzled source k-block) ----
  const int cks = t & 3;
  auto mksrc = [&](int c) -> const short* {
    const short* base; int row;
    if (c < BM_) { base = Ahi; row = m0 + c; }
    else if (c < 2 * BM_) { base = Alo; row = m0 + c - BM_; }
    else if (c < 2 * BM_ + BN_) { base = Whi; row = n0 + c - 2 * BM_; }
    else { base = Wlo; row = n0 + c - 2 * BM_ - BN_; }
    return base + (size_t)row * K + (cks ^ ((c >> 1) & 3)) * 8;
  };
  const short* sp[OPS_FULL + 1];
#pragma unroll
  for (int o = 0; o < OPS_FULL; ++o) sp[o] = mksrc(o * 128 + (t >> 2));
  if (REM) sp[OPS_FULL] = mksrc((t < 256) ? (OPS_FULL * 128 + (t >> 2)) : 0);

  auto stage = [&](int buf, int k0) {
    short* base = lds + buf * BUFSH;
#pragma unroll
    for (int o = 0; o < OPS_FULL; ++o)
      gl2lds16(sp[o] + k0, base + o * 4096 + w * 512);
    if (REM) {
      if (t < 256)
        gl2lds16(sp[OPS_FULL] + k0, base + OPS_FULL * 4096 + w * 512);
    }
  };

  const int kb_r = (lh ^ ((l >> 1) & 3)) * 8;

  // bias preload (oldest vmem, keeps the vmcnt ledger conservative-safe)
  float bv[NR];
#pragma unroll
  for (int ni = 0; ni < NR; ++ni) bv[ni] = bias[n0 + wc * WN_ + ni * 16 + li];

  f32x4 acc[MR][NR] = {};
  const int ns = K >> 5;

  stage(0, 0);

  for (int s = 0; s < ns; ++s) {
    const int bp = s & 1;
    __builtin_amdgcn_s_barrier();  // B1: buf bp^1 free to overwrite
    if (s + 1 < ns) {
      stage(bp ^ 1, (s + 1) * 32);
      __builtin_amdgcn_sched_barrier(0);
      if (REM) {
        if (w < 4)
          asm volatile("s_waitcnt vmcnt(%0)" ::"n"(OPS_FULL + 1) : "memory");
        else
          asm volatile("s_waitcnt vmcnt(%0)" ::"n"(OPS_FULL) : "memory");
      } else {
        asm volatile("s_waitcnt vmcnt(%0)" ::"n"(OPS_FULL) : "memory");
      }
    } else {
      __builtin_amdgcn_sched_barrier(0);
      asm volatile("s_waitcnt vmcnt(0)" ::: "memory");
    }
    __builtin_amdgcn_s_barrier();  // B2: publish buf bp

    const short* bufp = lds + bp * BUFSH;
    bf16x8 ah[MR], al[MR];
#pragma unroll
    for (int mi = 0; mi < MR; ++mi) {
      int row = wr * WM_ + mi * 16 + li;
      ah[mi] = *(const bf16x8*)(bufp + row * 32 + kb_r);
      al[mi] = *(const bf16x8*)(bufp + BM_ * 32 + row * 32 + kb_r);
    }
    __builtin_amdgcn_s_setprio(1);
#pragma unroll
    for (int ni = 0; ni < NR; ++ni) {
      int rowB = wc * WN_ + ni * 16 + li;
      bf16x8 bh = *(const bf16x8*)(bufp + 2 * BM_ * 32 + rowB * 32 + kb_r);
      bf16x8 bl = *(const bf16x8*)(bufp + (2 * BM_ + BN_) * 32 + rowB * 32 + kb_r);
#pragma unroll
      for (int mi = 0; mi < MR; ++mi) {
        acc[mi][ni] = __builtin_amdgcn_mfma_f32_16x16x32_bf16(ah[mi], bh, acc[mi][ni], 0, 0, 0);
        acc[mi][ni] = __builtin_amdgcn_mfma_f32_16x16x32_bf16(ah[mi], bl, acc[mi][ni], 0, 0, 0);
        acc[mi][ni] = __builtin_amdgcn_mfma_f32_16x16x32_bf16(al[mi], bh, acc[mi][ni], 0, 0, 0);
      }
    }
    __builtin_amdgcn_s_setprio(0);
  }

  // ---- epilogue ----
  const int col_l = l & 15;
  const int row_l = (l >> 4) * 4;
#pragma unroll
  for (int mi = 0; mi < MR; ++mi) {
#pragma unroll
    for (int ni = 0; ni < NR; ++ni) {
      int col = n0 + wc * WN_ + ni * 16 + col_l;
      float bvv = bv[ni];
#pragma unroll
      for (int r = 0; r < 4; ++r) {
        int row = m0 + wr * WM_ + mi * 16 + row_l + r;
        float v = acc[mi][ni][r] + bvv;
        if (RES) v += Rres[(size_t)row * N + col];
        if (ACT == 1) v = fmaxf(v, 0.f);
        if (ACT == 2) v = tanhf(v);
        if (OSPLIT) {
          short h2, l2;
          split_bf16(v, h2, l2);
          Chi[(size_t)row * N + col] = h2;
          Clo[(size_t)row * N + col] = l2;
        } else {
          Cf[(size_t)row * N + col] = v;
        }
      }
    }
  }
}

// ---------------- MFMA split-bf16 attention (f32 qkv input) -----------------
__global__ __launch_bounds__(256, 2) void attn_kernel(
    const float* __restrict__ qkv, short* __restrict__ t1h,
    short* __restrict__ t1l) {
  __shared__ short lds[16384];
  const int qt = blockIdx.x, h = blockIdx.y, b = blockIdx.z;
  const int t = threadIdx.x;
  const int w = t >> 6, l = t & 63;
  const int li = l & 15, lh = l >> 4;

  short* kh = lds;
  short* kl = lds + 4096;
  short* ph = lds + 8192 + w * 2048;
  short* pl = ph + 1024;

  const int tok0 = b * S_ + qt * 64;

  bf16x8 qh[2], ql[2];
  {
    const float* qrow = qkv + (size_t)(tok0 + w * 16 + li) * 2304 + h * 64 + lh * 8;
#pragma unroll
    for (int s = 0; s < 2; s++) {
      float4 f0 = *(const float4*)(qrow + s * 32);
      float4 f1 = *(const float4*)(qrow + s * 32 + 4);
      float f[8] = {f0.x, f0.y, f0.z, f0.w, f1.x, f1.y, f1.z, f1.w};
      bf16x8 hv, lv;
#pragma unroll
      for (int j = 0; j < 8; j++) {
        short hs, ls2;
        split_bf16(f[j], hs, ls2);
        hv[j] = hs; lv[j] = ls2;
      }
      qh[s] = hv; ql[s] = lv;
    }
  }

  const int skk = t >> 2, sd0 = (t & 3) * 16;

  f32x4 acc[16] = {};

  const float* kbase = qkv + (size_t)(b * S_) * 2304 + 768 + h * 64;
#pragma unroll
  for (int c = 0; c < 4; c++) {
    __syncthreads();
    {
      const float* src = kbase + (size_t)(c * 64 + skk) * 2304 + sd0;
#pragma unroll
      for (int i = 0; i < 4; i++) {
        float4 f = *(const float4*)(src + i * 4);
        int d = sd0 + i * 4;
        short4 hv, lv;
        split_bf16(f.x, hv.x, lv.x);
        split_bf16(f.y, hv.y, lv.y);
        split_bf16(f.z, hv.z, lv.z);
        split_bf16(f.w, hv.w, lv.w);
        int off = skk * 64 + ((((d >> 3) ^ (skk & 7)) & 7) << 3) + (d & 7);
        *(short4*)(kh + off) = hv;
        *(short4*)(kl + off) = lv;
      }
    }
    __syncthreads();
#pragma unroll
    for (int nn = 0; nn < 4; nn++) {
      const int krow = nn * 16 + li;
#pragma unroll
      for (int s = 0; s < 2; s++) {
        const int off = krow * 64 + ((((s * 4 + lh) ^ (li & 7)) & 7) << 3);
        bf16x8 bh = *(const bf16x8*)(kh + off);
        bf16x8 bl = *(const bf16x8*)(kl + off);
        acc[c * 4 + nn] = __builtin_amdgcn_mfma_f32_16x16x32_bf16(qh[s], bh, acc[c * 4 + nn], 0, 0, 0);
        acc[c * 4 + nn] = __builtin_amdgcn_mfma_f32_16x16x32_bf16(qh[s], bl, acc[c * 4 + nn], 0, 0, 0);
        acc[c * 4 + nn] = __builtin_amdgcn_mfma_f32_16x16x32_bf16(ql[s], bh, acc[c * 4 + nn], 0, 0, 0);
      }
    }
  }

  float rs_[4];
#pragma unroll
  for (int r = 0; r < 4; r++) {
    float m = -3.4e38f;
#pragma unroll
    for (int fi = 0; fi < 16; fi++) m = fmaxf(m, acc[fi][r]);
#pragma unroll
    for (int off = 8; off; off >>= 1) m = fmaxf(m, __shfl_xor(m, off));
    float sum = 0.f;
#pragma unroll
    for (int fi = 0; fi < 16; fi++) {
      float p = expf((acc[fi][r] - m) * 0.125f);
      acc[fi][r] = p;
      sum += p;
    }
#pragma unroll
    for (int off = 8; off; off >>= 1) sum += __shfl_xor(sum, off);
    rs_[r] = sum;
  }

  f32x4 oacc[4] = {};
  const float* vbase = qkv + (size_t)(b * S_) * 2304 + 1536 + h * 64;
#pragma unroll
  for (int c = 0; c < 4; c++) {
    __syncthreads();
    {
      const float* src = vbase + (size_t)(c * 64 + skk) * 2304 + sd0;
#pragma unroll
      for (int i = 0; i < 4; i++) {
        float4 f = *(const float4*)(src + i * 4);
        float fv[4] = {f.x, f.y, f.z, f.w};
#pragma unroll
        for (int j = 0; j < 4; j++) {
          int d = sd0 + i * 4 + j;
          short hs, ls2;
          split_bf16(fv[j], hs, ls2);
          int sw = (d & 7) ^ ((d >> 3) & 7);
          int off = d * 64 + ((((skk >> 3) ^ sw) & 7) << 3) + (skk & 7);
          kh[off] = hs;
          kl[off] = ls2;
        }
      }
    }
#pragma unroll
    for (int nn = 0; nn < 4; nn++) {
#pragma unroll
      for (int r = 0; r < 4; r++) {
        const int q = lh * 4 + r;
        const int keyl = li + 16 * nn;
        short hs, ls2;
        split_bf16(acc[c * 4 + nn][r], hs, ls2);
        const int off = q * 64 + ((((keyl >> 3) ^ (q & 7)) & 7) << 3) + (keyl & 7);
        ph[off] = hs;
        pl[off] = ls2;
      }
    }
    __syncthreads();
    bf16x8 pah[2], pal[2];
#pragma unroll
    for (int s = 0; s < 2; s++) {
      const int off = li * 64 + ((((s * 4 + lh) ^ (li & 7)) & 7) << 3);
      pah[s] = *(const bf16x8*)(ph + off);
      pal[s] = *(const bf16x8*)(pl + off);
    }
#pragma unroll
    for (int dn = 0; dn < 4; dn++) {
      const int drow = dn * 16 + li;
      const int sw = ((drow & 7) ^ ((drow >> 3) & 7)) & 7;
#pragma unroll
      for (int s = 0; s < 2; s++) {
        const int off = drow * 64 + ((((s * 4 + lh) ^ sw) & 7) << 3);
        bf16x8 vh = *(const bf16x8*)(kh + off);
        bf16x8 vl = *(const bf16x8*)(kl + off);
        oacc[dn] = __builtin_amdgcn_mfma_f32_16x16x32_bf16(pah[s], vh, oacc[dn], 0, 0, 0);
        oacc[dn] = __builtin_amdgcn_mfma_f32_16x16x32_bf16(pah[s], vl, oacc[dn], 0, 0, 0);
        oacc[dn] = __builtin_amdgcn_mfma_f32_16x16x32_bf16(pal[s], vh, oacc[dn], 0, 0, 0);
      }
    }
  }

  float rinv[4];
#pragma unroll
  for (int r = 0; r < 4; r++) rinv[r] = 1.f / rs_[r];
#pragma unroll
  for (int dn = 0; dn < 4; dn++) {
#pragma unroll
    for (int r = 0; r < 4; r++) {
      float v = oacc[dn][r] * rinv[r];
      short hs, ls2;
      split_bf16(v, hs, ls2);
      size_t oidx = (size_t)(tok0 + w * 16 + lh * 4 + r) * E_ + h * 64 + dn * 16 + li;
      t1h[oidx] = hs;
      t1l[oidx] = ls2;
    }
  }
}

// ---------------- cosine similarity ----------------
__global__ __launch_bounds__(256) void cos_kernel(
    const float* __restrict__ a, const float* __restrict__ o,
    float* __restrict__ cosv) {
  int row = blockIdx.x;
  int t = threadIdx.x;
  const float* ar = a + (size_t)row * E_;
  const float* orr = o + (size_t)row * E_;
  float d = 0.f, na = 0.f, nb = 0.f;
#pragma unroll
  for (int j = 0; j < 3; j++) {
    float av = ar[t + 256 * j], ov = orr[t + 256 * j];
    d = fmaf(av, ov, d);
    na = fmaf(av, av, na);
    nb = fmaf(ov, ov, nb);
  }
  d = block_sum256(d);
  na = block_sum256(na);
  nb = block_sum256(nb);
  if (t == 0) cosv[row] = d / fmaxf(sqrtf(na) * sqrtf(nb), 1e-8f);
}

// ---------------- final selection: rank-based parallel top-k ----------------
__global__ __launch_bounds__(256) void select_kernel(
    const float* __restrict__ cosv, const int* __restrict__ typ,
    const float* __restrict__ gh, const float* __restrict__ gt,
    float* __restrict__ out) {
  __shared__ float vals[256];
  int b = blockIdx.x, t = threadIdx.x;
  int idx = b * 256 + t;
  int ty = typ[idx];
  float c = cosv[idx];
  float res = 0.f;

  float eh = (ty == 1) ? expf(c) : 0.f;
  float sh = block_sum256(eh);
  float glh = (ty == 1) ? (logf(eh / sh) + gh[idx]) : NEGV;
  vals[t] = glh;
  __syncthreads();
  {
    int rank = 0;
#pragma unroll
    for (int j = 0; j < 64; ++j) {
      float4 q = *(const float4*)&vals[j * 4];
      rank += (q.x > glh) || (q.x == glh && (j * 4 + 0) < t);
      rank += (q.y > glh) || (q.y == glh && (j * 4 + 1) < t);
      rank += (q.z > glh) || (q.z == glh && (j * 4 + 2) < t);
      rank += (q.w > glh) || (q.w == glh && (j * 4 + 3) < t);
    }
    if (ty == 1 && rank < 64) res += 1.f;
  }
  __syncthreads();

  float et = (ty == 2) ? expf(c) : 0.f;
  float st = block_sum256(et);
  float glt = (ty == 2) ? (logf(1.f - et / st) + gt[idx]) : NEGV;
  vals[t] = glt;
  __syncthreads();
  {
    int rank = 0;
#pragma unroll
    for (int j = 0; j < 64; ++j) {
      float4 q = *(const float4*)&vals[j * 4];
      rank += (q.x > glt) || (q.x == glt && (j * 4 + 0) < t);
      rank += (q.y > glt) || (q.y == glt && (j * 4 + 1) < t);
      rank += (q.z > glt) || (q.z == glt && (j * 4 + 2) < t);
      rank += (q.w > glt) || (q.w == glt && (j * 4 + 3) < t);
    }
    if (ty == 2 && rank < 63) res += 1.f;
  }
  out[idx] = res;
}

extern "C" void kernel_launch(void* const* d_in, const int* in_sizes, int n_in,
                              void* d_out, int out_size, void* d_ws,
                              size_t ws_size, hipStream_t stream) {
  const float* tok = (const float*)d_in[0];
  const int* pos = (const int*)d_in[2];
  const int* typ = (const int*)d_in[3];
  const float* gh = (const float*)d_in[4];
  const float* gt = (const float*)d_in[5];
  const float* pe = (const float*)d_in[6];
  const float* temb = (const float*)d_in[7];
  const float* ln_w = (const float*)d_in[8];
  const float* ln_b = (const float*)d_in[9];
  const float* dense_w = (const float*)d_in[10];
  const float* dense_b = (const float*)d_in[11];
  const float* qkv_w = (const float*)d_in[12];
  const float* qkv_b = (const float*)d_in[13];
  const float* out_w = (const float*)d_in[14];
  const float* out_b = (const float*)d_in[15];
  const float* ln1_w = (const float*)d_in[16];
  const float* ln1_b = (const float*)d_in[17];
  const float* lin1_w = (const float*)d_in[18];
  const float* lin1_b = (const float*)d_in[19];
  const float* lin2_w = (const float*)d_in[20];
  const float* lin2_b = (const float*)d_in[21];
  const float* ln2_w = (const float*)d_in[22];
  const float* ln2_b = (const float*)d_in[23];

  const int M = B_ * S_;
  const size_t NX = (size_t)M * E_;
  const size_t NQKV = (size_t)M * 3 * E_;
  const size_t NFF = (size_t)M * FF_;

  const size_t oQ = 0;
  const size_t oO = oQ + 2 * (size_t)3 * E_ * E_;
  const size_t oL1 = oO + 2 * (size_t)E_ * E_;
  const size_t oL2 = oL1 + 2 * (size_t)FF_ * E_;
  const size_t oD = oL2 + 2 * (size_t)E_ * FF_;
  const size_t WTOT = oD + (size_t)E_ * E_;

  float* ws = (float*)d_ws;
  float* x = ws;
  float* t2 = x + NX;
  float* shared = t2 + NX;
  short* x_hi = (short*)(shared + NQKV);
  short* x_lo = x_hi + NX;
  short* t1_hi = x_lo + NX;
  short* t1_lo = t1_hi + NX;
  short* w_hi = t1_lo + NX;
  short* w_lo = w_hi + WTOT;
  float* cosb = (float*)(w_lo + WTOT);

  short* big_hi = (short*)shared;  // aliases qkv f32 region (disjoint lifetime)
  short* big_lo = big_hi + NFF;

  // ---- split weights into bf16 hi/lo planes ----
  {
    int n4;
    n4 = (int)(2 * 3 * E_ * E_ / 4);
    split_kernel<<<(n4 + 255) / 256, 256, 0, stream>>>(qkv_w, w_hi + oQ, w_lo + oQ, n4);
    n4 = (int)(2 * E_ * E_ / 4);
    split_kernel<<<(n4 + 255) / 256, 256, 0, stream>>>(out_w, w_hi + oO, w_lo + oO, n4);
    n4 = (int)(2 * FF_ * E_ / 4);
    split_kernel<<<(n4 + 255) / 256, 256, 0, stream>>>(lin1_w, w_hi + oL1, w_lo + oL1, n4);
    n4 = (int)(2 * E_ * FF_ / 4);
    split_kernel<<<(n4 + 255) / 256, 256, 0, stream>>>(lin2_w, w_hi + oL2, w_lo + oL2, n4);
    n4 = (int)(E_ * E_ / 4);
    split_kernel<<<(n4 + 255) / 256, 256, 0, stream>>>(dense_w, w_hi + oD, w_lo + oD, n4);
  }

  // ---- embed + LN ----
  embed_ln_kernel<<<M, 256, 0, stream>>>(tok, pos, typ, pe, temb, ln_w, ln_b,
                                         x, x_hi, x_lo);

  for (int l = 0; l < L_; l++) {
    const size_t wq = oQ + (size_t)l * 3 * E_ * E_;
    const size_t wo = oO + (size_t)l * E_ * E_;
    const size_t w1 = oL1 + (size_t)l * FF_ * E_;
    const size_t w2 = oL2 + (size_t)l * E_ * FF_;
    // qkv = x @ qkv_w^T + b -> f32 (shared). 256x288 blocks, grid 32x8=256.
    gemm_big<288, 64, 144, 0, 0, 0><<<256, 512, 0, stream>>>(
        x_hi, x_lo, w_hi + wq, w_lo + wq, qkv_b + (size_t)l * 3 * E_, nullptr,
        shared, nullptr, nullptr, M, 3 * E_, E_, 3 * E_ / 288, 32);
    // attention -> t1 splits (MFMA)
    attn_kernel<<<dim3(4, H_, B_), 256, 0, stream>>>(shared, t1_hi, t1_lo);
    // t2 = x + t1 @ out_w^T + b. 256x96 blocks, grid 32x8=256.
    gemm_big<96, 64, 48, 0, 1, 0><<<256, 512, 0, stream>>>(
        t1_hi, t1_lo, w_hi + wo, w_lo + wo, out_b + (size_t)l * E_, x, t2,
        nullptr, nullptr, M, E_, E_, E_ / 96, 32);
    // x = LN(t2)
    ln_kernel<<<M, 256, 0, stream>>>(t2, ln1_w + (size_t)l * E_,
                                     ln1_b + (size_t)l * E_, x, x_hi, x_lo);
    // big = relu(x @ lin1_w^T + b) -> splits. 256x256 blocks, grid 32x8=256.
    gemm_big<256, 128, 64, 1, 0, 1><<<256, 512, 0, stream>>>(
        x_hi, x_lo, w_hi + w1, w_lo + w1, lin1_b + (size_t)l * FF_, nullptr,
        nullptr, big_hi, big_lo, M, FF_, E_, FF_ / 256, 32);
    // t2 = x + big @ lin2_w^T + b. 256x96 blocks, grid 32x8=256.
    gemm_big<96, 64, 48, 0, 1, 0><<<256, 512, 0, stream>>>(
        big_hi, big_lo, w_hi + w2, w_lo + w2, lin2_b + (size_t)l * E_, x, t2,
        nullptr, nullptr, M, E_, FF_, E_ / 96, 32);
    // x = LN(t2)
    ln_kernel<<<M, 256, 0, stream>>>(t2, ln2_w + (size_t)l * E_,
                                     ln2_b + (size_t)l * E_, x, x_hi, x_lo);
  }

  // final LN -> splits only (f32 output dead; skip the write)
  ln_kernel<<<M, 256, 0, stream>>>(x, ln_w, ln_b, nullptr, t1_hi, t1_lo);
  // dense: tanh(t1 @ dense_w^T + b) -> f32 (shared region). 256x96 blocks.
  gemm_big<96, 64, 48, 2, 0, 0><<<256, 512, 0, stream>>>(
      t1_hi, t1_lo, w_hi + oD, w_lo + oD, dense_b, nullptr, shared, nullptr,
      nullptr, M, E_, E_, E_ / 96, 32);
  // cos
  cos_kernel<<<M, 256, 0, stream>>>(tok, shared, cosb);
  // selection
  select_kernel<<<B_, 256, 0, stream>>>(cosb, typ, gh, gt, (float*)d_out);
}

// Round 14
// 796.735 us; speedup vs baseline: 1.0238x; 1.0238x over previous
//
#include <hip/hip_runtime.h>
#include <math.h>

#define B_ 32
#define S_ 256
#define E_ 768
#define H_ 12
#define L_ 2
#define FF_ 2048
#define NEGV -1e30f

typedef __attribute__((ext_vector_type(8))) short bf16x8;
typedef __attribute__((ext_vector_type(4))) float f32x4;

// ---------- bf16 split helpers ----------
__device__ __forceinline__ short bf16_rne(float x) {
  unsigned u = __float_as_uint(x);
  u += 0x7fffu + ((u >> 16) & 1u);
  return (short)(u >> 16);
}
__device__ __forceinline__ float bf16_to_f32(short h) {
  return __uint_as_float(((unsigned)(unsigned short)h) << 16);
}
__device__ __forceinline__ void split_bf16(float v, short& h, short& l) {
  h = bf16_rne(v);
  l = bf16_rne(v - bf16_to_f32(h));
}

__device__ __forceinline__ void gl2lds16(const short* g, short* s) {
  __builtin_amdgcn_global_load_lds((const __attribute__((address_space(1))) void*)g,
                                   (__attribute__((address_space(3))) void*)s, 16, 0, 0);
}

// ---------------- block-wide sum over 256 threads ----------------
__device__ __forceinline__ float block_sum256(float v) {
  __shared__ float sh[4];
  int lane = threadIdx.x & 63, w = threadIdx.x >> 6;
#pragma unroll
  for (int off = 32; off; off >>= 1) v += __shfl_down(v, off);
  if (lane == 0) sh[w] = v;
  __syncthreads();
  float tot = sh[0] + sh[1] + sh[2] + sh[3];
  __syncthreads();
  return tot;
}

// ---------------- embed + LN (emits f32 + bf16 split planes) ----------------
__global__ __launch_bounds__(256) void embed_ln_kernel(
    const float* __restrict__ tok, const int* __restrict__ pos,
    const int* __restrict__ typ, const float* __restrict__ pe,
    const float* __restrict__ temb, const float* __restrict__ w,
    const float* __restrict__ b, float* __restrict__ out,
    short* __restrict__ ohi, short* __restrict__ olo) {
  int row = blockIdx.x;
  int t = threadIdx.x;
  int p = pos[row], ty = typ[row];
  const float* tr = tok + (size_t)row * E_;
  const float* pr = pe + (size_t)p * E_;
  const float* yr = temb + (size_t)ty * E_;
  float v0 = tr[t] + pr[t] + yr[t];
  float v1 = tr[t + 256] + pr[t + 256] + yr[t + 256];
  float v2 = tr[t + 512] + pr[t + 512] + yr[t + 512];
  float m = block_sum256(v0 + v1 + v2) * (1.f / E_);
  float d0 = v0 - m, d1 = v1 - m, d2 = v2 - m;
  float var = block_sum256(d0 * d0 + d1 * d1 + d2 * d2) * (1.f / E_);
  float rs = 1.f / sqrtf(var + 1e-5f);
  size_t base = (size_t)row * E_;
  float r0 = d0 * rs * w[t] + b[t];
  float r1 = d1 * rs * w[t + 256] + b[t + 256];
  float r2 = d2 * rs * w[t + 512] + b[t + 512];
  out[base + t] = r0; out[base + t + 256] = r1; out[base + t + 512] = r2;
  short h, l;
  split_bf16(r0, h, l); ohi[base + t] = h; olo[base + t] = l;
  split_bf16(r1, h, l); ohi[base + t + 256] = h; olo[base + t + 256] = l;
  split_bf16(r2, h, l); ohi[base + t + 512] = h; olo[base + t + 512] = l;
}

// ---------------- LN (emits optional f32 + bf16 split planes) ---------------
__global__ __launch_bounds__(256) void ln_kernel(
    const float* __restrict__ in, const float* __restrict__ w,
    const float* __restrict__ b, float* __restrict__ out,
    short* __restrict__ ohi, short* __restrict__ olo) {
  int row = blockIdx.x;
  int t = threadIdx.x;
  const float* p = in + (size_t)row * E_;
  float v0 = p[t], v1 = p[t + 256], v2 = p[t + 512];
  float m = block_sum256(v0 + v1 + v2) * (1.f / E_);
  float d0 = v0 - m, d1 = v1 - m, d2 = v2 - m;
  float var = block_sum256(d0 * d0 + d1 * d1 + d2 * d2) * (1.f / E_);
  float rs = 1.f / sqrtf(var + 1e-5f);
  size_t base = (size_t)row * E_;
  float r0 = d0 * rs * w[t] + b[t];
  float r1 = d1 * rs * w[t + 256] + b[t + 256];
  float r2 = d2 * rs * w[t + 512] + b[t + 512];
  if (out) {
    out[base + t] = r0; out[base + t + 256] = r1; out[base + t + 512] = r2;
  }
  short h, l;
  split_bf16(r0, h, l); ohi[base + t] = h; olo[base + t] = l;
  split_bf16(r1, h, l); ohi[base + t + 256] = h; olo[base + t + 256] = l;
  split_bf16(r2, h, l); ohi[base + t + 512] = h; olo[base + t + 512] = l;
}

// ---------------- weight split: f32 -> (hi, lo) bf16 planes ----------------
__global__ __launch_bounds__(256) void split_kernel(
    const float* __restrict__ src, short* __restrict__ hi,
    short* __restrict__ lo, int n4) {
  int i = blockIdx.x * 256 + threadIdx.x;
  if (i >= n4) return;
  float4 v = ((const float4*)src)[i];
  short4 h, l;
  split_bf16(v.x, h.x, l.x);
  split_bf16(v.y, h.y, l.y);
  split_bf16(v.z, h.z, l.z);
  split_bf16(v.w, h.w, l.w);
  ((short4*)hi)[i] = h;
  ((short4*)lo)[i] = l;
}

// ---------------- 256-row 8-wave split-bf16 MFMA GEMM, 3-phase schedule -----
// Block 256 x BN_, 512 thr = 8 waves, joint 3-pass.  Per K-step, 3 phases:
// phase p = { issue 1/3 of next-tile stage ops ; (p0: counted vmcnt + barrier)
// ; ds_read B-frag group p (+ A-frags at p0) ; setprio MFMA group ; barrier }.
// Loads issue interleaved with MFMA clusters -> latency hidden; barriers give
// the CU scheduler wave role-split (T5 pays).  Ledger: p0 issues P0CNT ops
// then vmcnt(P0CNT) waits exactly tile-s's loads.  Grid = 256 blocks (1/CU)
// for BN in {288 (qkv), 256 (lin1), 96 (out/lin2/dense)}.
template <int BN_, int WM_, int WN_, int ACT, int RES, int OSPLIT>
__global__ __launch_bounds__(512, 2) void gemm_big(
    const short* __restrict__ Ahi, const short* __restrict__ Alo,
    const short* __restrict__ Whi, const short* __restrict__ Wlo,
    const float* __restrict__ bias, const float* __restrict__ Rres,
    float* __restrict__ Cf, short* __restrict__ Chi, short* __restrict__ Clo,
    int M, int N, int K, int nx, int cpx) {
  constexpr int BM_ = 256;
  constexpr int MR = WM_ / 16, NR = WN_ / 16;
  constexpr int NWC = BN_ / WN_;
  constexpr int CHUNKS = 2 * BM_ + 2 * BN_;     // 1088 / 1024 / 704
  constexpr int OPS_FULL = CHUNKS / 128;        // 8 / 8 / 5
  constexpr int REM = CHUNKS - OPS_FULL * 128;  // 64 / 0 / 64
  constexpr int BUFSH = CHUNKS * 32;
  constexpr int P0CNT = (OPS_FULL + 2) / 3;     // ops issued in phase 0
  constexpr int G0E = (NR + 2) / 3;             // ni group boundaries
  constexpr int G1E = G0E + (NR + 1) / 3;

  __shared__ short lds[2 * BUFSH];
  const int t = threadIdx.x;
  const int l = t & 63;
  const int w = t >> 6;
  const int wr = w / NWC, wc = w % NWC;
  const int li = l & 15, lh = l >> 4;

  int id = blockIdx.x;
  int id2 = (id & 7) * cpx + (id >> 3);
  const int n0 = (id2 % nx) * BN_, m0 = (id2 / nx) * BM_;

  // ---- staging source pointers (chunk map, XOR-swizzled source k-block) ----
  const int cks = t & 3;
  auto mksrc = [&](int c) -> const short* {
    const short* base; int row;
    if (c < BM_) { base = Ahi; row = m0 + c; }
    else if (c < 2 * BM_) { base = Alo; row = m0 + c - BM_; }
    else if (c < 2 * BM_ + BN_) { base = Whi; row = n0 + c - 2 * BM_; }
    else { base = Wlo; row = n0 + c - 2 * BM_ - BN_; }
    return base + (size_t)row * K + (cks ^ ((c >> 1) & 3)) * 8;
  };
  const short* sp[OPS_FULL + 1];
#pragma unroll
  for (int o = 0; o < OPS_FULL; ++o) sp[o] = mksrc(o * 128 + (t >> 2));
  if (REM) sp[OPS_FULL] = mksrc((t < 256) ? (OPS_FULL * 128 + (t >> 2)) : 0);

  // stage portion p of a tile (p in 0..2; REM half-op rides phase 2)
  auto stage_p = [&](int buf, int k0, int p) {
    short* base = lds + buf * BUFSH;
#pragma unroll
    for (int o = 0; o < OPS_FULL; ++o)
      if (o % 3 == p)
        gl2lds16(sp[o] + k0, base + o * 4096 + w * 512);
    if (REM && p == 2) {
      if (t < 256)
        gl2lds16(sp[OPS_FULL] + k0, base + OPS_FULL * 4096 + w * 512);
    }
  };

  const int kb_r = (lh ^ ((l >> 1) & 3)) * 8;

  // bias preload (oldest vmem; vmcnt ledger stays conservative-safe)
  float bv[NR];
#pragma unroll
  for (int ni = 0; ni < NR; ++ni) bv[ni] = bias[n0 + wc * WN_ + ni * 16 + li];

  f32x4 acc[MR][NR] = {};
  const int ns = K >> 5;

  // prologue: full stage of tile 0
  stage_p(0, 0, 0);
  stage_p(0, 0, 1);
  stage_p(0, 0, 2);

  for (int s = 0; s < ns; ++s) {
    const int bp = s & 1;
    const bool pf = (s + 1 < ns);
    const int k1 = (s + 1) * 32;
    const short* bufp = lds + bp * BUFSH;

    bf16x8 ah[MR], al[MR];

    // ---------------- phase 0 ----------------
    if (pf) stage_p(bp ^ 1, k1, 0);
    __builtin_amdgcn_sched_barrier(0);
    if (pf) {
      asm volatile("s_waitcnt vmcnt(%0)" ::"n"(P0CNT) : "memory");
    } else {
      asm volatile("s_waitcnt vmcnt(0)" ::: "memory");
    }
    __builtin_amdgcn_s_barrier();
#pragma unroll
    for (int mi = 0; mi < MR; ++mi) {
      int row = wr * WM_ + mi * 16 + li;
      ah[mi] = *(const bf16x8*)(bufp + row * 32 + kb_r);
      al[mi] = *(const bf16x8*)(bufp + BM_ * 32 + row * 32 + kb_r);
    }
    __builtin_amdgcn_s_setprio(1);
#pragma unroll
    for (int ni = 0; ni < G0E; ++ni) {
      int rowB = wc * WN_ + ni * 16 + li;
      bf16x8 bh = *(const bf16x8*)(bufp + 2 * BM_ * 32 + rowB * 32 + kb_r);
      bf16x8 bl = *(const bf16x8*)(bufp + (2 * BM_ + BN_) * 32 + rowB * 32 + kb_r);
#pragma unroll
      for (int mi = 0; mi < MR; ++mi) {
        acc[mi][ni] = __builtin_amdgcn_mfma_f32_16x16x32_bf16(ah[mi], bh, acc[mi][ni], 0, 0, 0);
        acc[mi][ni] = __builtin_amdgcn_mfma_f32_16x16x32_bf16(ah[mi], bl, acc[mi][ni], 0, 0, 0);
        acc[mi][ni] = __builtin_amdgcn_mfma_f32_16x16x32_bf16(al[mi], bh, acc[mi][ni], 0, 0, 0);
      }
    }
    __builtin_amdgcn_s_setprio(0);
    __builtin_amdgcn_s_barrier();

    // ---------------- phase 1 ----------------
    if (pf) stage_p(bp ^ 1, k1, 1);
    __builtin_amdgcn_s_setprio(1);
#pragma unroll
    for (int ni = G0E; ni < G1E; ++ni) {
      int rowB = wc * WN_ + ni * 16 + li;
      bf16x8 bh = *(const bf16x8*)(bufp + 2 * BM_ * 32 + rowB * 32 + kb_r);
      bf16x8 bl = *(const bf16x8*)(bufp + (2 * BM_ + BN_) * 32 + rowB * 32 + kb_r);
#pragma unroll
      for (int mi = 0; mi < MR; ++mi) {
        acc[mi][ni] = __builtin_amdgcn_mfma_f32_16x16x32_bf16(ah[mi], bh, acc[mi][ni], 0, 0, 0);
        acc[mi][ni] = __builtin_amdgcn_mfma_f32_16x16x32_bf16(ah[mi], bl, acc[mi][ni], 0, 0, 0);
        acc[mi][ni] = __builtin_amdgcn_mfma_f32_16x16x32_bf16(al[mi], bh, acc[mi][ni], 0, 0, 0);
      }
    }
    __builtin_amdgcn_s_setprio(0);
    __builtin_amdgcn_s_barrier();

    // ---------------- phase 2 ----------------
    if (pf) stage_p(bp ^ 1, k1, 2);
    __builtin_amdgcn_s_setprio(1);
#pragma unroll
    for (int ni = G1E; ni < NR; ++ni) {
      int rowB = wc * WN_ + ni * 16 + li;
      bf16x8 bh = *(const bf16x8*)(bufp + 2 * BM_ * 32 + rowB * 32 + kb_r);
      bf16x8 bl = *(const bf16x8*)(bufp + (2 * BM_ + BN_) * 32 + rowB * 32 + kb_r);
#pragma unroll
      for (int mi = 0; mi < MR; ++mi) {
        acc[mi][ni] = __builtin_amdgcn_mfma_f32_16x16x32_bf16(ah[mi], bh, acc[mi][ni], 0, 0, 0);
        acc[mi][ni] = __builtin_amdgcn_mfma_f32_16x16x32_bf16(ah[mi], bl, acc[mi][ni], 0, 0, 0);
        acc[mi][ni] = __builtin_amdgcn_mfma_f32_16x16x32_bf16(al[mi], bh, acc[mi][ni], 0, 0, 0);
      }
    }
    __builtin_amdgcn_s_setprio(0);
    // ds_reads above completed (lgkm waits precede MFMA issue, in-order), so
    // after this barrier the next iteration may safely overwrite buf bp.
    __builtin_amdgcn_s_barrier();
  }

  // ---- epilogue ----
  const int col_l = l & 15;
  const int row_l = (l >> 4) * 4;
#pragma unroll
  for (int mi = 0; mi < MR; ++mi) {
#pragma unroll
    for (int ni = 0; ni < NR; ++ni) {
      int col = n0 + wc * WN_ + ni * 16 + col_l;
      float bvv = bv[ni];
#pragma unroll
      for (int r = 0; r < 4; ++r) {
        int row = m0 + wr * WM_ + mi * 16 + row_l + r;
        float v = acc[mi][ni][r] + bvv;
        if (RES) v += Rres[(size_t)row * N + col];
        if (ACT == 1) v = fmaxf(v, 0.f);
        if (ACT == 2) v = tanhf(v);
        if (OSPLIT) {
          short h2, l2;
          split_bf16(v, h2, l2);
          Chi[(size_t)row * N + col] = h2;
          Clo[(size_t)row * N + col] = l2;
        } else {
          Cf[(size_t)row * N + col] = v;
        }
      }
    }
  }
}

// ---------------- MFMA split-bf16 attention (f32 qkv input) -----------------
__global__ __launch_bounds__(256, 2) void attn_kernel(
    const float* __restrict__ qkv, short* __restrict__ t1h,
    short* __restrict__ t1l) {
  __shared__ short lds[16384];
  const int qt = blockIdx.x, h = blockIdx.y, b = blockIdx.z;
  const int t = threadIdx.x;
  const int w = t >> 6, l = t & 63;
  const int li = l & 15, lh = l >> 4;

  short* kh = lds;
  short* kl = lds + 4096;
  short* ph = lds + 8192 + w * 2048;
  short* pl = ph + 1024;

  const int tok0 = b * S_ + qt * 64;

  bf16x8 qh[2], ql[2];
  {
    const float* qrow = qkv + (size_t)(tok0 + w * 16 + li) * 2304 + h * 64 + lh * 8;
#pragma unroll
    for (int s = 0; s < 2; s++) {
      float4 f0 = *(const float4*)(qrow + s * 32);
      float4 f1 = *(const float4*)(qrow + s * 32 + 4);
      float f[8] = {f0.x, f0.y, f0.z, f0.w, f1.x, f1.y, f1.z, f1.w};
      bf16x8 hv, lv;
#pragma unroll
      for (int j = 0; j < 8; j++) {
        short hs, ls2;
        split_bf16(f[j], hs, ls2);
        hv[j] = hs; lv[j] = ls2;
      }
      qh[s] = hv; ql[s] = lv;
    }
  }

  const int skk = t >> 2, sd0 = (t & 3) * 16;

  f32x4 acc[16] = {};

  const float* kbase = qkv + (size_t)(b * S_) * 2304 + 768 + h * 64;
#pragma unroll
  for (int c = 0; c < 4; c++) {
    __syncthreads();
    {
      const float* src = kbase + (size_t)(c * 64 + skk) * 2304 + sd0;
#pragma unroll
      for (int i = 0; i < 4; i++) {
        float4 f = *(const float4*)(src + i * 4);
        int d = sd0 + i * 4;
        short4 hv, lv;
        split_bf16(f.x, hv.x, lv.x);
        split_bf16(f.y, hv.y, lv.y);
        split_bf16(f.z, hv.z, lv.z);
        split_bf16(f.w, hv.w, lv.w);
        int off = skk * 64 + ((((d >> 3) ^ (skk & 7)) & 7) << 3) + (d & 7);
        *(short4*)(kh + off) = hv;
        *(short4*)(kl + off) = lv;
      }
    }
    __syncthreads();
#pragma unroll
    for (int nn = 0; nn < 4; nn++) {
      const int krow = nn * 16 + li;
#pragma unroll
      for (int s = 0; s < 2; s++) {
        const int off = krow * 64 + ((((s * 4 + lh) ^ (li & 7)) & 7) << 3);
        bf16x8 bh = *(const bf16x8*)(kh + off);
        bf16x8 bl = *(const bf16x8*)(kl + off);
        acc[c * 4 + nn] = __builtin_amdgcn_mfma_f32_16x16x32_bf16(qh[s], bh, acc[c * 4 + nn], 0, 0, 0);
        acc[c * 4 + nn] = __builtin_amdgcn_mfma_f32_16x16x32_bf16(qh[s], bl, acc[c * 4 + nn], 0, 0, 0);
        acc[c * 4 + nn] = __builtin_amdgcn_mfma_f32_16x16x32_bf16(ql[s], bh, acc[c * 4 + nn], 0, 0, 0);
      }
    }
  }

  float rs_[4];
#pragma unroll
  for (int r = 0; r < 4; r++) {
    float m = -3.4e38f;
#pragma unroll
    for (int fi = 0; fi < 16; fi++) m = fmaxf(m, acc[fi][r]);
#pragma unroll
    for (int off = 8; off; off >>= 1) m = fmaxf(m, __shfl_xor(m, off));
    float sum = 0.f;
#pragma unroll
    for (int fi = 0; fi < 16; fi++) {
      float p = expf((acc[fi][r] - m) * 0.125f);
      acc[fi][r] = p;
      sum += p;
    }
#pragma unroll
    for (int off = 8; off; off >>= 1) sum += __shfl_xor(sum, off);
    rs_[r] = sum;
  }

  f32x4 oacc[4] = {};
  const float* vbase = qkv + (size_t)(b * S_) * 2304 + 1536 + h * 64;
#pragma unroll
  for (int c = 0; c < 4; c++) {
    __syncthreads();
    {
      const float* src = vbase + (size_t)(c * 64 + skk) * 2304 + sd0;
#pragma unroll
      for (int i = 0; i < 4; i++) {
        float4 f = *(const float4*)(src + i * 4);
        float fv[4] = {f.x, f.y, f.z, f.w};
#pragma unroll
        for (int j = 0; j < 4; j++) {
          int d = sd0 + i * 4 + j;
          short hs, ls2;
          split_bf16(fv[j], hs, ls2);
          int sw = (d & 7) ^ ((d >> 3) & 7);
          int off = d * 64 + ((((skk >> 3) ^ sw) & 7) << 3) + (skk & 7);
          kh[off] = hs;
          kl[off] = ls2;
        }
      }
    }
#pragma unroll
    for (int nn = 0; nn < 4; nn++) {
#pragma unroll
      for (int r = 0; r < 4; r++) {
        const int q = lh * 4 + r;
        const int keyl = li + 16 * nn;
        short hs, ls2;
        split_bf16(acc[c * 4 + nn][r], hs, ls2);
        const int off = q * 64 + ((((keyl >> 3) ^ (q & 7)) & 7) << 3) + (keyl & 7);
        ph[off] = hs;
        pl[off] = ls2;
      }
    }
    __syncthreads();
    bf16x8 pah[2], pal[2];
#pragma unroll
    for (int s = 0; s < 2; s++) {
      const int off = li * 64 + ((((s * 4 + lh) ^ (li & 7)) & 7) << 3);
      pah[s] = *(const bf16x8*)(ph + off);
      pal[s] = *(const bf16x8*)(pl + off);
    }
#pragma unroll
    for (int dn = 0; dn < 4; dn++) {
      const int drow = dn * 16 + li;
      const int sw = ((drow & 7) ^ ((drow >> 3) & 7)) & 7;
#pragma unroll
      for (int s = 0; s < 2; s++) {
        const int off = drow * 64 + ((((s * 4 + lh) ^ sw) & 7) << 3);
        bf16x8 vh = *(const bf16x8*)(kh + off);
        bf16x8 vl = *(const bf16x8*)(kl + off);
        oacc[dn] = __builtin_amdgcn_mfma_f32_16x16x32_bf16(pah[s], vh, oacc[dn], 0, 0, 0);
        oacc[dn] = __builtin_amdgcn_mfma_f32_16x16x32_bf16(pah[s], vl, oacc[dn], 0, 0, 0);
        oacc[dn] = __builtin_amdgcn_mfma_f32_16x16x32_bf16(pal[s], vh, oacc[dn], 0, 0, 0);
      }
    }
  }

  float rinv[4];
#pragma unroll
  for (int r = 0; r < 4; r++) rinv[r] = 1.f / rs_[r];
#pragma unroll
  for (int dn = 0; dn < 4; dn++) {
#pragma unroll
    for (int r = 0; r < 4; r++) {
      float v = oacc[dn][r] * rinv[r];
      short hs, ls2;
      split_bf16(v, hs, ls2);
      size_t oidx = (size_t)(tok0 + w * 16 + lh * 4 + r) * E_ + h * 64 + dn * 16 + li;
      t1h[oidx] = hs;
      t1l[oidx] = ls2;
    }
  }
}

// ---------------- cosine similarity ----------------
__global__ __launch_bounds__(256) void cos_kernel(
    const float* __restrict__ a, const float* __restrict__ o,
    float* __restrict__ cosv) {
  int row = blockIdx.x;
  int t = threadIdx.x;
  const float* ar = a + (size_t)row * E_;
  const float* orr = o + (size_t)row * E_;
  float d = 0.f, na = 0.f, nb = 0.f;
#pragma unroll
  for (int j = 0; j < 3; j++) {
    float av = ar[t + 256 * j], ov = orr[t + 256 * j];
    d = fmaf(av, ov, d);
    na = fmaf(av, av, na);
    nb = fmaf(ov, ov, nb);
  }
  d = block_sum256(d);
  na = block_sum256(na);
  nb = block_sum256(nb);
  if (t == 0) cosv[row] = d / fmaxf(sqrtf(na) * sqrtf(nb), 1e-8f);
}

// ---------------- final selection: rank-based parallel top-k ----------------
__global__ __launch_bounds__(256) void select_kernel(
    const float* __restrict__ cosv, const int* __restrict__ typ,
    const float* __restrict__ gh, const float* __restrict__ gt,
    float* __restrict__ out) {
  __shared__ float vals[256];
  int b = blockIdx.x, t = threadIdx.x;
  int idx = b * 256 + t;
  int ty = typ[idx];
  float c = cosv[idx];
  float res = 0.f;

  float eh = (ty == 1) ? expf(c) : 0.f;
  float sh = block_sum256(eh);
  float glh = (ty == 1) ? (logf(eh / sh) + gh[idx]) : NEGV;
  vals[t] = glh;
  __syncthreads();
  {
    int rank = 0;
#pragma unroll
    for (int j = 0; j < 64; ++j) {
      float4 q = *(const float4*)&vals[j * 4];
      rank += (q.x > glh) || (q.x == glh && (j * 4 + 0) < t);
      rank += (q.y > glh) || (q.y == glh && (j * 4 + 1) < t);
      rank += (q.z > glh) || (q.z == glh && (j * 4 + 2) < t);
      rank += (q.w > glh) || (q.w == glh && (j * 4 + 3) < t);
    }
    if (ty == 1 && rank < 64) res += 1.f;
  }
  __syncthreads();

  float et = (ty == 2) ? expf(c) : 0.f;
  float st = block_sum256(et);
  float glt = (ty == 2) ? (logf(1.f - et / st) + gt[idx]) : NEGV;
  vals[t] = glt;
  __syncthreads();
  {
    int rank = 0;
#pragma unroll
    for (int j = 0; j < 64; ++j) {
      float4 q = *(const float4*)&vals[j * 4];
      rank += (q.x > glt) || (q.x == glt && (j * 4 + 0) < t);
      rank += (q.y > glt) || (q.y == glt && (j * 4 + 1) < t);
      rank += (q.z > glt) || (q.z == glt && (j * 4 + 2) < t);
      rank += (q.w > glt) || (q.w == glt && (j * 4 + 3) < t);
    }
    if (ty == 2 && rank < 63) res += 1.f;
  }
  out[idx] = res;
}

extern "C" void kernel_launch(void* const* d_in, const int* in_sizes, int n_in,
                              void* d_out, int out_size, void* d_ws,
                              size_t ws_size, hipStream_t stream) {
  const float* tok = (const float*)d_in[0];
  const int* pos = (const int*)d_in[2];
  const int* typ = (const int*)d_in[3];
  const float* gh = (const float*)d_in[4];
  const float* gt = (const float*)d_in[5];
  const float* pe = (const float*)d_in[6];
  const float* temb = (const float*)d_in[7];
  const float* ln_w = (const float*)d_in[8];
  const float* ln_b = (const float*)d_in[9];
  const float* dense_w = (const float*)d_in[10];
  const float* dense_b = (const float*)d_in[11];
  const float* qkv_w = (const float*)d_in[12];
  const float* qkv_b = (const float*)d_in[13];
  const float* out_w = (const float*)d_in[14];
  const float* out_b = (const float*)d_in[15];
  const float* ln1_w = (const float*)d_in[16];
  const float* ln1_b = (const float*)d_in[17];
  const float* lin1_w = (const float*)d_in[18];
  const float* lin1_b = (const float*)d_in[19];
  const float* lin2_w = (const float*)d_in[20];
  const float* lin2_b = (const float*)d_in[21];
  const float* ln2_w = (const float*)d_in[22];
  const float* ln2_b = (const float*)d_in[23];

  const int M = B_ * S_;
  const size_t NX = (size_t)M * E_;
  const size_t NQKV = (size_t)M * 3 * E_;
  const size_t NFF = (size_t)M * FF_;

  const size_t oQ = 0;
  const size_t oO = oQ + 2 * (size_t)3 * E_ * E_;
  const size_t oL1 = oO + 2 * (size_t)E_ * E_;
  const size_t oL2 = oL1 + 2 * (size_t)FF_ * E_;
  const size_t oD = oL2 + 2 * (size_t)E_ * FF_;
  const size_t WTOT = oD + (size_t)E_ * E_;

  float* ws = (float*)d_ws;
  float* x = ws;
  float* t2 = x + NX;
  float* shared = t2 + NX;
  short* x_hi = (short*)(shared + NQKV);
  short* x_lo = x_hi + NX;
  short* t1_hi = x_lo + NX;
  short* t1_lo = t1_hi + NX;
  short* w_hi = t1_lo + NX;
  short* w_lo = w_hi + WTOT;
  float* cosb = (float*)(w_lo + WTOT);

  short* big_hi = (short*)shared;  // aliases qkv f32 region (disjoint lifetime)
  short* big_lo = big_hi + NFF;

  // ---- split weights into bf16 hi/lo planes ----
  {
    int n4;
    n4 = (int)(2 * 3 * E_ * E_ / 4);
    split_kernel<<<(n4 + 255) / 256, 256, 0, stream>>>(qkv_w, w_hi + oQ, w_lo + oQ, n4);
    n4 = (int)(2 * E_ * E_ / 4);
    split_kernel<<<(n4 + 255) / 256, 256, 0, stream>>>(out_w, w_hi + oO, w_lo + oO, n4);
    n4 = (int)(2 * FF_ * E_ / 4);
    split_kernel<<<(n4 + 255) / 256, 256, 0, stream>>>(lin1_w, w_hi + oL1, w_lo + oL1, n4);
    n4 = (int)(2 * E_ * FF_ / 4);
    split_kernel<<<(n4 + 255) / 256, 256, 0, stream>>>(lin2_w, w_hi + oL2, w_lo + oL2, n4);
    n4 = (int)(E_ * E_ / 4);
    split_kernel<<<(n4 + 255) / 256, 256, 0, stream>>>(dense_w, w_hi + oD, w_lo + oD, n4);
  }

  // ---- embed + LN ----
  embed_ln_kernel<<<M, 256, 0, stream>>>(tok, pos, typ, pe, temb, ln_w, ln_b,
                                         x, x_hi, x_lo);

  for (int l = 0; l < L_; l++) {
    const size_t wq = oQ + (size_t)l * 3 * E_ * E_;
    const size_t wo = oO + (size_t)l * E_ * E_;
    const size_t w1 = oL1 + (size_t)l * FF_ * E_;
    const size_t w2 = oL2 + (size_t)l * E_ * FF_;
    // qkv = x @ qkv_w^T + b -> f32 (shared). 256x288 blocks, grid 32x8=256.
    gemm_big<288, 64, 144, 0, 0, 0><<<256, 512, 0, stream>>>(
        x_hi, x_lo, w_hi + wq, w_lo + wq, qkv_b + (size_t)l * 3 * E_, nullptr,
        shared, nullptr, nullptr, M, 3 * E_, E_, 3 * E_ / 288, 32);
    // attention -> t1 splits (MFMA)
    attn_kernel<<<dim3(4, H_, B_), 256, 0, stream>>>(shared, t1_hi, t1_lo);
    // t2 = x + t1 @ out_w^T + b. 256x96 blocks, grid 32x8=256.
    gemm_big<96, 64, 48, 0, 1, 0><<<256, 512, 0, stream>>>(
        t1_hi, t1_lo, w_hi + wo, w_lo + wo, out_b + (size_t)l * E_, x, t2,
        nullptr, nullptr, M, E_, E_, E_ / 96, 32);
    // x = LN(t2)
    ln_kernel<<<M, 256, 0, stream>>>(t2, ln1_w + (size_t)l * E_,
                                     ln1_b + (size_t)l * E_, x, x_hi, x_lo);
    // big = relu(x @ lin1_w^T + b) -> splits. 256x256 blocks, grid 32x8=256.
    gemm_big<256, 128, 64, 1, 0, 1><<<256, 512, 0, stream>>>(
        x_hi, x_lo, w_hi + w1, w_lo + w1, lin1_b + (size_t)l * FF_, nullptr,
        nullptr, big_hi, big_lo, M, FF_, E_, FF_ / 256, 32);
    // t2 = x + big @ lin2_w^T + b. 256x96 blocks, grid 32x8=256.
    gemm_big<96, 64, 48, 0, 1, 0><<<256, 512, 0, stream>>>(
        big_hi, big_lo, w_hi + w2, w_lo + w2, lin2_b + (size_t)l * E_, x, t2,
        nullptr, nullptr, M, E_, FF_, E_ / 96, 32);
    // x = LN(t2)
    ln_kernel<<<M, 256, 0, stream>>>(t2, ln2_w + (size_t)l * E_,
                                     ln2_b + (size_t)l * E_, x, x_hi, x_lo);
  }

  // final LN -> splits only (f32 output dead; skip the write)
  ln_kernel<<<M, 256, 0, stream>>>(x, ln_w, ln_b, nullptr, t1_hi, t1_lo);
  // dense: tanh(t1 @ dense_w^T + b) -> f32 (shared region). 256x96 blocks.
  gemm_big<96, 64, 48, 2, 0, 0><<<256, 512, 0, stream>>>(
      t1_hi, t1_lo, w_hi + oD, w_lo + oD, dense_b, nullptr, shared, nullptr,
      nullptr, M, E_, E_, E_ / 96, 32);
  // cos
  cos_kernel<<<M, 256, 0, stream>>>(tok, shared, cosb);
  // selection
  select_kernel<<<B_, 256, 0, stream>>>(cosb, typ, gh, gt, (float*)d_out);
}